// Round 3
// baseline (2051.287 us; speedup 1.0000x reference)
//
#include <hip/hip_runtime.h>
#include <stdint.h>

#define N_NODES 100000
#define N_EDGES 400000
#define N_GRAPHS 2000
#define C_IN 48
#define HD 128
#define NLAYERS 6
#define BN_EPS 1e-5f
#define NSLOPE 0.01f
#define SB 391  // ceil(N_NODES/256)

typedef uint16_t u16;
typedef uint32_t u32;

__device__ __forceinline__ float bf2f_lo(u32 v) { return __uint_as_float(v << 16); }
__device__ __forceinline__ float bf2f_hi(u32 v) { return __uint_as_float(v & 0xffff0000u); }
__device__ __forceinline__ float bf2f(u16 h) { return __uint_as_float(((u32)h) << 16); }
__device__ __forceinline__ u16 f2bf(float f) {
    u32 u = __float_as_uint(f);
    u32 r = (u + 0x7fffu + ((u >> 16) & 1u)) >> 16;
    return (u16)r;
}
__device__ __forceinline__ u32 pack2(float a, float b) {
    return (u32)f2bf(a) | ((u32)f2bf(b) << 16);
}
__device__ __forceinline__ float lrelu(float v) { return v >= 0.f ? v : v * NSLOPE; }

// dtype detection: mode=1 -> float inputs are fp32; mode=0 -> bf16.
__global__ __launch_bounds__(256) void detect_kernel(const u16* __restrict__ x, int* __restrict__ mode) {
    __shared__ int flag;
    if (threadIdx.x == 0) flag = 0;
    __syncthreads();
    int local = 0;
    for (int i = threadIdx.x; i < 16384; i += 256) {
        float a = fabsf(bf2f(x[i]));
        if (!(a < 1e4f)) local = 1;  // big, inf, or NaN => fp32 data
    }
    if (local) flag = 1;
    __syncthreads();
    if (threadIdx.x == 0) mode[0] = flag;
}

// ---------------- CSR build ----------------
__global__ __launch_bounds__(256) void hist_kernel(const int* __restrict__ dst, int* __restrict__ cnt) {
    int e = blockIdx.x * 256 + threadIdx.x;
    if (e < N_EDGES) atomicAdd(&cnt[dst[e]], 1);
}

__global__ __launch_bounds__(256) void scan1_kernel(const int* __restrict__ cnt, int* __restrict__ bsum) {
    __shared__ int s[256];
    const int t = threadIdx.x;
    const int i = blockIdx.x * 256 + t;
    s[t] = (i < N_NODES) ? cnt[i] : 0;
    __syncthreads();
    for (int d = 128; d > 0; d >>= 1) {
        if (t < d) s[t] += s[t + d];
        __syncthreads();
    }
    if (t == 0) bsum[blockIdx.x] = s[0];
}

__global__ __launch_bounds__(512) void scan2_kernel(int* __restrict__ bsum, int* __restrict__ row_ptr) {
    __shared__ int s[SB];
    const int t = threadIdx.x;
    if (t < SB) s[t] = bsum[t];
    __syncthreads();
    if (t == 0) {
        int run = 0;
        for (int b = 0; b < SB; ++b) { int v = s[b]; s[b] = run; run += v; }
        row_ptr[0] = 0;
    }
    __syncthreads();
    if (t < SB) bsum[t] = s[t];
}

__global__ __launch_bounds__(256) void scan3_kernel(const int* __restrict__ cnt, const int* __restrict__ bsum,
                                                    int* __restrict__ row_ptr) {
    __shared__ int s[256];
    const int t = threadIdx.x;
    const int i = blockIdx.x * 256 + t;
    s[t] = (i < N_NODES) ? cnt[i] : 0;
    __syncthreads();
    if (t == 0) {
        int run = bsum[blockIdx.x];
        for (int j = 0; j < 256; ++j) { run += s[j]; s[j] = run; }
    }
    __syncthreads();
    if (i < N_NODES) row_ptr[i + 1] = s[t];
}

__global__ __launch_bounds__(256) void fill_kernel(const int* __restrict__ src, const int* __restrict__ dst,
                                                   int* __restrict__ cursor, int* __restrict__ col_idx) {
    int e = blockIdx.x * 256 + threadIdx.x;
    if (e < N_EDGES) {
        int d = dst[e];
        int slot = atomicAdd(&cursor[d], 1);
        col_idx[slot] = src[e];
    }
}

// w1pad is ALWAYS f32 (internal); reads W1a per mode.
__global__ __launch_bounds__(256) void pad_w1_kernel(const void* __restrict__ W1a, const int* __restrict__ mode,
                                                     float* __restrict__ w1pad) {
    int idx = blockIdx.x * 256 + threadIdx.x;  // 16384
    int k = idx >> 7, j = idx & 127;
    float v = 0.f;
    if (k < C_IN)
        v = (*mode) ? ((const float*)W1a)[k * HD + j] : bf2f(((const u16*)W1a)[k * HD + j]);
    w1pad[idx] = v;
}

// ---------------- aggregation ----------------
__global__ __launch_bounds__(256) void agg0_kernel(const void* __restrict__ xv, const int* __restrict__ row_ptr,
                                                   const int* __restrict__ col_idx, const int* __restrict__ mode,
                                                   u16* __restrict__ z) {
    const int wave = threadIdx.x >> 6, lane = threadIdx.x & 63;
    const int node = blockIdx.x * 4 + wave;
    if (node >= N_NODES) return;
    const int md = *mode;
    u32 outw = 0u;
    if (lane < 24) {
        const int s = row_ptr[node], e = row_ptr[node + 1];
        float a0, a1;
        if (md) {
            const float* xf = (const float*)xv;
            float2 v = *reinterpret_cast<const float2*>(xf + (size_t)node * C_IN + 2 * lane);
            a0 = v.x; a1 = v.y;
            for (int t = s; t < e; ++t) {
                int src = col_idx[t];
                float2 w = *reinterpret_cast<const float2*>(xf + (size_t)src * C_IN + 2 * lane);
                a0 += w.x; a1 += w.y;
            }
        } else {
            const u16* xh = (const u16*)xv;
            u32 v = *reinterpret_cast<const u32*>(xh + (size_t)node * C_IN + 2 * lane);
            a0 = bf2f_lo(v); a1 = bf2f_hi(v);
            for (int t = s; t < e; ++t) {
                int src = col_idx[t];
                u32 w = *reinterpret_cast<const u32*>(xh + (size_t)src * C_IN + 2 * lane);
                a0 += bf2f_lo(w); a1 += bf2f_hi(w);
            }
        }
        outw = pack2(a0, a1);
    }
    *reinterpret_cast<u32*>(z + (size_t)node * HD + 2 * lane) = outw;
}

__global__ __launch_bounds__(256) void agg_kernel(const u16* __restrict__ h, const int* __restrict__ row_ptr,
                                                  const int* __restrict__ col_idx, u16* __restrict__ z) {
    const int wave = threadIdx.x >> 6, lane = threadIdx.x & 63;
    const int node = blockIdx.x * 4 + wave;
    if (node >= N_NODES) return;
    u32 v = *reinterpret_cast<const u32*>(h + (size_t)node * HD + 2 * lane);
    float a0 = bf2f_lo(v), a1 = bf2f_hi(v);
    const int s = row_ptr[node], e = row_ptr[node + 1];
    for (int t = s; t < e; ++t) {
        int src = col_idx[t];
        u32 w = *reinterpret_cast<const u32*>(h + (size_t)src * HD + 2 * lane);
        a0 += bf2f_lo(w); a1 += bf2f_hi(w);
    }
    *reinterpret_cast<u32*>(z + (size_t)node * HD + 2 * lane) = pack2(a0, a1);
}

// ---------------- GEMM ----------------
// W/bias: if WF32CONST !=0, W is the internal f32 w1pad (ignore mode for W).
// Otherwise W dtype follows mode. welem/belem are ELEMENT offsets applied per-dtype on device.
// IN-PLACE SAFE (out may == A).
template <int TRANS, int WF32CONST>
__global__ __launch_bounds__(256) void gemm_kernel(const u16* A, const void* __restrict__ Wv, size_t welem,
                                                   const void* __restrict__ biasv, size_t belem,
                                                   const float* __restrict__ tA, const float* __restrict__ tB,
                                                   const int* __restrict__ mode, u16* out) {
    __shared__ float As[64][33];
    __shared__ float Bs[32][128];
    const int md = *mode;
    const int tid = threadIdx.x;
    const int tx8 = (tid & 15) * 8;
    const int ty4 = (tid >> 4) * 4;
    const int m0 = blockIdx.x * 64;
    const int arow = tid >> 2;
    const int ako = (tid & 3) << 3;
    const int bk = tid >> 3;
    const int bco = (tid & 7) << 4;
    float acc[4][8];
    #pragma unroll
    for (int r = 0; r < 4; ++r)
        #pragma unroll
        for (int j = 0; j < 8; ++j) acc[r][j] = 0.f;

    for (int k0 = 0; k0 < HD; k0 += 32) {
        float av[8];
        if (m0 + arow < N_NODES) {
            const uint4 v = *reinterpret_cast<const uint4*>(A + (size_t)(m0 + arow) * HD + k0 + ako);
            const u32 w[4] = {v.x, v.y, v.z, v.w};
            #pragma unroll
            for (int i = 0; i < 4; ++i) { av[2 * i] = bf2f_lo(w[i]); av[2 * i + 1] = bf2f_hi(w[i]); }
            if (TRANS) {
                #pragma unroll
                for (int i = 0; i < 8; ++i) av[i] = lrelu(tA[k0 + ako + i] * av[i] + tB[k0 + ako + i]);
            }
        } else {
            #pragma unroll
            for (int i = 0; i < 8; ++i) av[i] = 0.f;
        }
        #pragma unroll
        for (int i = 0; i < 8; ++i) As[arow][ako + i] = av[i];
        {
            const size_t we = welem + (size_t)(k0 + bk) * HD + bco;
            float bv[16];
            if (WF32CONST || md) {
                const float* wp = (const float*)Wv + we;
                #pragma unroll
                for (int q = 0; q < 4; ++q) {
                    const float4 f = reinterpret_cast<const float4*>(wp)[q];
                    bv[4 * q] = f.x; bv[4 * q + 1] = f.y; bv[4 * q + 2] = f.z; bv[4 * q + 3] = f.w;
                }
            } else {
                const u16* wp = (const u16*)Wv + we;
                const uint4 v0 = *reinterpret_cast<const uint4*>(wp);
                const uint4 v1 = *reinterpret_cast<const uint4*>(wp + 8);
                const u32 w0[4] = {v0.x, v0.y, v0.z, v0.w}, w1[4] = {v1.x, v1.y, v1.z, v1.w};
                #pragma unroll
                for (int i = 0; i < 4; ++i) {
                    bv[2 * i] = bf2f_lo(w0[i]); bv[2 * i + 1] = bf2f_hi(w0[i]);
                    bv[8 + 2 * i] = bf2f_lo(w1[i]); bv[8 + 2 * i + 1] = bf2f_hi(w1[i]);
                }
            }
            #pragma unroll
            for (int q = 0; q < 4; ++q) {
                float4 f; f.x = bv[4 * q]; f.y = bv[4 * q + 1]; f.z = bv[4 * q + 2]; f.w = bv[4 * q + 3];
                *reinterpret_cast<float4*>(&Bs[bk][bco + 4 * q]) = f;
            }
        }
        __syncthreads();
        #pragma unroll 8
        for (int k = 0; k < 32; ++k) {
            const float aa[4] = {As[ty4 + 0][k], As[ty4 + 1][k], As[ty4 + 2][k], As[ty4 + 3][k]};
            const float4 b0 = *reinterpret_cast<const float4*>(&Bs[k][tx8]);
            const float4 b1v = *reinterpret_cast<const float4*>(&Bs[k][tx8 + 4]);
            const float bb[8] = {b0.x, b0.y, b0.z, b0.w, b1v.x, b1v.y, b1v.z, b1v.w};
            #pragma unroll
            for (int r = 0; r < 4; ++r)
                #pragma unroll
                for (int j = 0; j < 8; ++j) acc[r][j] = fmaf(aa[r], bb[j], acc[r][j]);
        }
        __syncthreads();
    }
    float bj[8];
    #pragma unroll
    for (int j = 0; j < 8; ++j)
        bj[j] = md ? ((const float*)biasv)[belem + tx8 + j] : bf2f(((const u16*)biasv)[belem + tx8 + j]);
    #pragma unroll
    for (int r = 0; r < 4; ++r) {
        const int m = m0 + ty4 + r;
        if (m < N_NODES) {
            uint4 o;
            o.x = pack2(acc[r][0] + bj[0], acc[r][1] + bj[1]);
            o.y = pack2(acc[r][2] + bj[2], acc[r][3] + bj[3]);
            o.z = pack2(acc[r][4] + bj[4], acc[r][5] + bj[5]);
            o.w = pack2(acc[r][6] + bj[6], acc[r][7] + bj[7]);
            *reinterpret_cast<uint4*>(out + (size_t)m * HD + tx8) = o;
        }
    }
}

// ---------------- BN stats / finalize / apply ----------------
__global__ __launch_bounds__(256) void colstats_kernel(const u16* __restrict__ X, float* __restrict__ stats) {
    const int cp = threadIdx.x & 63;
    const int rg = threadIdx.x >> 6;
    float s0 = 0, s1 = 0, q0 = 0, q1 = 0;
    for (int r = blockIdx.x * 4 + rg; r < N_NODES; r += gridDim.x * 4) {
        const u32 v = *reinterpret_cast<const u32*>(X + (size_t)r * HD + 2 * cp);
        const float a = bf2f_lo(v), b = bf2f_hi(v);
        s0 += a; q0 += a * a; s1 += b; q1 += b * b;
    }
    atomicAdd(&stats[2 * cp], s0);
    atomicAdd(&stats[2 * cp + 1], s1);
    atomicAdd(&stats[128 + 2 * cp], q0);
    atomicAdd(&stats[128 + 2 * cp + 1], q1);
}

__global__ __launch_bounds__(128) void finalize_kernel(float* __restrict__ stats, const void* __restrict__ gammav,
                                                       const void* __restrict__ betav, size_t elem,
                                                       const int* __restrict__ mode) {
    const int j = threadIdx.x;
    const int md = *mode;
    const float inv_n = 1.0f / (float)N_NODES;
    float mean = stats[j] * inv_n;
    float var = stats[128 + j] * inv_n - mean * mean;
    var = fmaxf(var, 0.f);
    float rs = rsqrtf(var + BN_EPS);
    float g  = md ? ((const float*)gammav)[elem + j] : bf2f(((const u16*)gammav)[elem + j]);
    float be = md ? ((const float*)betav)[elem + j]  : bf2f(((const u16*)betav)[elem + j]);
    float A = g * rs;
    stats[256 + j] = A;
    stats[384 + j] = be - A * mean;
}

__global__ __launch_bounds__(256) void bnapply_kernel(const u16* __restrict__ u, const float* __restrict__ A,
                                                      const float* __restrict__ B, u16* __restrict__ h) {
    const size_t idx = (size_t)blockIdx.x * 256 + threadIdx.x;
    if (idx >= (size_t)N_NODES * 64) return;
    const int j0 = (int)(idx & 63) * 2;
    const u32 v = reinterpret_cast<const u32*>(u)[idx];
    float a = lrelu(A[j0] * bf2f_lo(v) + B[j0]);
    float b = lrelu(A[j0 + 1] * bf2f_hi(v) + B[j0 + 1]);
    reinterpret_cast<u32*>(h)[idx] = pack2(a, b);
}

// ---------------- pooling + head ----------------
__global__ __launch_bounds__(128) void pool_kernel(const u16* __restrict__ hf, const int* __restrict__ batch,
                                                   const int* __restrict__ mode, float* __restrict__ emb,
                                                   void* __restrict__ outv) {
    const int g = blockIdx.x;
    const int j = threadIdx.x;
    const int md = *mode;
    int lo = 0, hi = N_NODES;
    while (lo < hi) { int m = (lo + hi) >> 1; if (batch[m] < g) lo = m + 1; else hi = m; }
    const int s = lo;
    hi = N_NODES;
    while (lo < hi) { int m = (lo + hi) >> 1; if (batch[m] < g + 1) lo = m + 1; else hi = m; }
    const int e = lo;
    const int cnt = e - s;
    float sum = 0.f, mx = -INFINITY;
    for (int n = s; n < e; ++n) {
        float v = bf2f(hf[(size_t)n * HD + j]);
        sum += v;
        mx = fmaxf(mx, v);
    }
    float mean = sum / (float)max(cnt, 1);
    if (cnt == 0) mx = 0.f;
    emb[(size_t)g * 256 + j] = mean;
    emb[(size_t)g * 256 + 128 + j] = mx;
    const size_t base = (size_t)N_GRAPHS * 3 + (size_t)g * 256;
    if (md) {
        ((float*)outv)[base + j] = mean;
        ((float*)outv)[base + 128 + j] = mx;
    } else {
        ((u16*)outv)[base + j] = f2bf(mean);
        ((u16*)outv)[base + 128 + j] = f2bf(mx);
    }
}

__global__ __launch_bounds__(64) void final_kernel(const float* __restrict__ emb, const void* __restrict__ fcwv,
                                                   const void* __restrict__ fcbv, const void* __restrict__ fc2wv,
                                                   const void* __restrict__ fc2bv, const int* __restrict__ mode,
                                                   void* __restrict__ outv) {
    __shared__ float es[256];
    __shared__ float hs[64];
    const int g = blockIdx.x, t = threadIdx.x;
    const int md = *mode;
    reinterpret_cast<float4*>(es)[t] = reinterpret_cast<const float4*>(emb + (size_t)g * 256)[t];
    __syncthreads();
    float acc = md ? ((const float*)fcbv)[t] : bf2f(((const u16*)fcbv)[t]);
    if (md) {
        const float* w = (const float*)fcwv;
        #pragma unroll 8
        for (int k = 0; k < 256; ++k) acc += es[k] * w[k * 64 + t];
    } else {
        const u16* w = (const u16*)fcwv;
        #pragma unroll 8
        for (int k = 0; k < 256; ++k) acc += es[k] * bf2f(w[k * 64 + t]);
    }
    hs[t] = lrelu(acc);
    __syncthreads();
    if (t < 3) {
        float o = md ? ((const float*)fc2bv)[t] : bf2f(((const u16*)fc2bv)[t]);
        if (md) {
            const float* w = (const float*)fc2wv;
            #pragma unroll 8
            for (int j = 0; j < 64; ++j) o += hs[j] * w[j * 3 + t];
            ((float*)outv)[(size_t)g * 3 + t] = o;
        } else {
            const u16* w = (const u16*)fc2wv;
            #pragma unroll 8
            for (int j = 0; j < 64; ++j) o += hs[j] * bf2f(w[j * 3 + t]);
            ((u16*)outv)[(size_t)g * 3 + t] = f2bf(o);
        }
    }
}

// ---------------- launch ----------------
static inline size_t align256(size_t x) { return (x + 255) & ~(size_t)255; }

extern "C" void kernel_launch(void* const* d_in, const int* in_sizes, int n_in,
                              void* d_out, int out_size, void* d_ws, size_t ws_size,
                              hipStream_t stream) {
    (void)in_sizes; (void)n_in; (void)out_size; (void)ws_size;
    const void* x    = d_in[0];
    const void* W1b  = d_in[3];
    const void* b1   = d_in[4];
    const void* g1   = d_in[5];
    const void* be1  = d_in[6];
    const void* W2   = d_in[7];
    const void* b2   = d_in[8];
    const void* gn   = d_in[9];
    const void* bnb  = d_in[10];
    const void* fcw  = d_in[11];
    const void* fcb  = d_in[12];
    const void* fc2w = d_in[13];
    const void* fc2b = d_in[14];
    const int* ei    = (const int*)d_in[15];
    const int* batch = (const int*)d_in[16];

    char* p = (char*)d_ws;
    size_t off = 0;
    u16* hb = (u16*)(p + off); off += align256((size_t)N_NODES * HD * 2);
    u16* zb = (u16*)(p + off); off += align256((size_t)N_NODES * HD * 2);
    float* w1pad = (float*)(p + off); off += align256((size_t)HD * HD * 4);
    float* emb = (float*)(p + off); off += align256((size_t)N_GRAPHS * 256 * 4);
    int* row_ptr = (int*)(p + off); off += align256((size_t)(N_NODES + 1) * 4);
    int* cursor = (int*)(p + off); off += align256((size_t)N_NODES * 4);
    int* col_idx = (int*)(p + off); off += align256((size_t)N_EDGES * 4);
    int* bsum = (int*)(p + off); off += align256((size_t)SB * 4);
    float* statsA = (float*)(p + off); off += align256(512 * 4);
    float* statsB = (float*)(p + off); off += align256(512 * 4);
    int* mode = (int*)(p + off); off += align256(4);

    const int EB = (N_EDGES + 255) / 256;
    const int GB = (N_NODES + 63) / 64;
    const int AB = (N_NODES + 3) / 4;

    detect_kernel<<<1, 256, 0, stream>>>((const u16*)x, mode);

    hipMemsetAsync(cursor, 0, (size_t)N_NODES * 4, stream);
    hist_kernel<<<EB, 256, 0, stream>>>(ei + N_EDGES, cursor);
    scan1_kernel<<<SB, 256, 0, stream>>>(cursor, bsum);
    scan2_kernel<<<1, 512, 0, stream>>>(bsum, row_ptr);
    scan3_kernel<<<SB, 256, 0, stream>>>(cursor, bsum, row_ptr);
    hipMemcpyAsync(cursor, row_ptr, (size_t)N_NODES * 4, hipMemcpyDeviceToDevice, stream);
    fill_kernel<<<EB, 256, 0, stream>>>(ei, ei + N_EDGES, cursor, col_idx);
    pad_w1_kernel<<<64, 256, 0, stream>>>(d_in[2], mode, w1pad);

    for (int l = 0; l < NLAYERS; ++l) {
        if (l == 0) {
            agg0_kernel<<<AB, 256, 0, stream>>>(x, row_ptr, col_idx, mode, zb);
        } else {
            bnapply_kernel<<<AB, 256, 0, stream>>>(zb, statsB + 256, statsB + 384, hb);
            agg_kernel<<<AB, 256, 0, stream>>>(hb, row_ptr, col_idx, zb);
        }
        const size_t voff = (size_t)l * HD;
        if (l == 0) {
            gemm_kernel<0, 1><<<GB, 256, 0, stream>>>(zb, w1pad, 0, b1, voff,
                                                      nullptr, nullptr, mode, zb);
        } else {
            gemm_kernel<0, 0><<<GB, 256, 0, stream>>>(zb, W1b, (size_t)(l - 1) * HD * HD, b1, voff,
                                                      nullptr, nullptr, mode, zb);
        }
        hipMemsetAsync(statsA, 0, 256 * 4, stream);
        colstats_kernel<<<256, 256, 0, stream>>>(zb, statsA);
        finalize_kernel<<<1, 128, 0, stream>>>(statsA, g1, be1, voff, mode);
        gemm_kernel<1, 0><<<GB, 256, 0, stream>>>(zb, W2, (size_t)l * HD * HD, b2, voff,
                                                  statsA + 256, statsA + 384, mode, zb);
        if (l < NLAYERS - 1) {
            hipMemsetAsync(statsB, 0, 256 * 4, stream);
            colstats_kernel<<<256, 256, 0, stream>>>(zb, statsB);
            finalize_kernel<<<1, 128, 0, stream>>>(statsB, gn, bnb, voff, mode);
        }
    }

    pool_kernel<<<N_GRAPHS, 128, 0, stream>>>(zb, batch, mode, emb, d_out);
    final_kernel<<<N_GRAPHS, 64, 0, stream>>>(emb, fcw, fcb, fc2w, fc2b, mode, d_out);
}

// Round 4
// 1109.115 us; speedup vs baseline: 1.8495x; 1.8495x over previous
//
#include <hip/hip_runtime.h>
#include <stdint.h>

#define N_NODES 100000
#define N_EDGES 400000
#define N_GRAPHS 2000
#define C_IN 48
#define HD 128
#define NLAYERS 6
#define BN_EPS 1e-5f
#define NSLOPE 0.01f
#define SB 391  // ceil(N_NODES/256)

typedef uint16_t u16;
typedef uint32_t u32;
typedef short bf16x8 __attribute__((ext_vector_type(8)));
typedef float f32x4 __attribute__((ext_vector_type(4)));

__device__ __forceinline__ float bf2f_lo(u32 v) { return __uint_as_float(v << 16); }
__device__ __forceinline__ float bf2f_hi(u32 v) { return __uint_as_float(v & 0xffff0000u); }
__device__ __forceinline__ float bf2f(u16 h) { return __uint_as_float(((u32)h) << 16); }
__device__ __forceinline__ u16 f2bf(float f) {
    u32 u = __float_as_uint(f);
    u32 r = (u + 0x7fffu + ((u >> 16) & 1u)) >> 16;
    return (u16)r;
}
__device__ __forceinline__ u32 pack2(float a, float b) {
    return (u32)f2bf(a) | ((u32)f2bf(b) << 16);
}
__device__ __forceinline__ float lrelu(float v) { return v >= 0.f ? v : v * NSLOPE; }

// dtype detection: mode=1 -> float inputs are fp32; mode=0 -> bf16.
__global__ __launch_bounds__(256) void detect_kernel(const u16* __restrict__ x, int* __restrict__ mode) {
    __shared__ int flag;
    if (threadIdx.x == 0) flag = 0;
    __syncthreads();
    int local = 0;
    for (int i = threadIdx.x; i < 16384; i += 256) {
        float a = fabsf(bf2f(x[i]));
        if (!(a < 1e4f)) local = 1;
    }
    if (local) flag = 1;
    __syncthreads();
    if (threadIdx.x == 0) mode[0] = flag;
}

// ---------------- CSR build ----------------
__global__ __launch_bounds__(256) void hist_kernel(const int* __restrict__ dst, int* __restrict__ cnt) {
    int e = blockIdx.x * 256 + threadIdx.x;
    if (e < N_EDGES) atomicAdd(&cnt[dst[e]], 1);
}

__global__ __launch_bounds__(256) void scan1_kernel(const int* __restrict__ cnt, int* __restrict__ bsum) {
    __shared__ int s[256];
    const int t = threadIdx.x;
    const int i = blockIdx.x * 256 + t;
    s[t] = (i < N_NODES) ? cnt[i] : 0;
    __syncthreads();
    for (int d = 128; d > 0; d >>= 1) {
        if (t < d) s[t] += s[t + d];
        __syncthreads();
    }
    if (t == 0) bsum[blockIdx.x] = s[0];
}

__global__ __launch_bounds__(512) void scan2_kernel(int* __restrict__ bsum, int* __restrict__ row_ptr) {
    __shared__ int s[SB];
    const int t = threadIdx.x;
    if (t < SB) s[t] = bsum[t];
    __syncthreads();
    if (t == 0) {
        int run = 0;
        for (int b = 0; b < SB; ++b) { int v = s[b]; s[b] = run; run += v; }
        row_ptr[0] = 0;
    }
    __syncthreads();
    if (t < SB) bsum[t] = s[t];
}

__global__ __launch_bounds__(256) void scan3_kernel(const int* __restrict__ cnt, const int* __restrict__ bsum,
                                                    int* __restrict__ row_ptr) {
    __shared__ int s[256];
    const int t = threadIdx.x;
    const int i = blockIdx.x * 256 + t;
    s[t] = (i < N_NODES) ? cnt[i] : 0;
    __syncthreads();
    if (t == 0) {
        int run = bsum[blockIdx.x];
        for (int j = 0; j < 256; ++j) { run += s[j]; s[j] = run; }
    }
    __syncthreads();
    if (i < N_NODES) row_ptr[i + 1] = s[t];
}

__global__ __launch_bounds__(256) void fill_kernel(const int* __restrict__ src, const int* __restrict__ dst,
                                                   int* __restrict__ cursor, int* __restrict__ col_idx) {
    int e = blockIdx.x * 256 + threadIdx.x;
    if (e < N_EDGES) {
        int d = dst[e];
        int slot = atomicAdd(&cursor[d], 1);
        col_idx[slot] = src[e];
    }
}

// ---------------- weight pre-pack into MFMA B-fragment layout (bf16) ----------------
// wpack[mat][f][lane][j] where f = kb*8+nt; b_frag element = W[kb*32 + (lane>>4)*8 + j][nt*16 + (lane&15)]
// mat 0 = layer-0 W1 (48x128 zero-padded to 128x128), mat 1..5 = W1b, mat 6..11 = W2.
__global__ __launch_bounds__(256) void pack_w_kernel(const void* __restrict__ W1a, const void* __restrict__ W1b,
                                                     const void* __restrict__ W2, const int* __restrict__ mode,
                                                     u16* __restrict__ wpack) {
    const int t = blockIdx.x * 256 + threadIdx.x;  // 12*2048 = 24576
    if (t >= 24576) return;
    const int mat = t >> 11;
    const int r = t & 2047;
    const int l = r & 63;
    const int f = r >> 6;
    const int kb = f >> 3, nt = f & 7;
    const int k0 = kb * 32 + (l >> 4) * 8;
    const int n = nt * 16 + (l & 15);
    const int md = *mode;
    u16 vals[8];
    #pragma unroll
    for (int j = 0; j < 8; ++j) {
        const int k = k0 + j;
        float v;
        if (mat == 0) {
            v = (k < C_IN) ? (md ? ((const float*)W1a)[k * HD + n] : bf2f(((const u16*)W1a)[k * HD + n])) : 0.f;
        } else if (mat < 6) {
            const size_t o = (size_t)(mat - 1) * HD * HD + (size_t)k * HD + n;
            v = md ? ((const float*)W1b)[o] : bf2f(((const u16*)W1b)[o]);
        } else {
            const size_t o = (size_t)(mat - 6) * HD * HD + (size_t)k * HD + n;
            v = md ? ((const float*)W2)[o] : bf2f(((const u16*)W2)[o]);
        }
        vals[j] = f2bf(v);
    }
    uint4 o;
    o.x = (u32)vals[0] | ((u32)vals[1] << 16);
    o.y = (u32)vals[2] | ((u32)vals[3] << 16);
    o.z = (u32)vals[4] | ((u32)vals[5] << 16);
    o.w = (u32)vals[6] | ((u32)vals[7] << 16);
    *reinterpret_cast<uint4*>(wpack + (size_t)t * 8) = o;
}

// ---------------- aggregation ----------------
__global__ __launch_bounds__(256) void agg0_kernel(const void* __restrict__ xv, const int* __restrict__ row_ptr,
                                                   const int* __restrict__ col_idx, const int* __restrict__ mode,
                                                   u16* __restrict__ z) {
    const int wave = threadIdx.x >> 6, lane = threadIdx.x & 63;
    const int node = blockIdx.x * 4 + wave;
    if (node >= N_NODES) return;
    const int md = *mode;
    u32 outw = 0u;
    if (lane < 24) {
        const int s = row_ptr[node], e = row_ptr[node + 1];
        float a0, a1;
        if (md) {
            const float* xf = (const float*)xv;
            float2 v = *reinterpret_cast<const float2*>(xf + (size_t)node * C_IN + 2 * lane);
            a0 = v.x; a1 = v.y;
            for (int t = s; t < e; ++t) {
                const int src = col_idx[t];
                float2 w = *reinterpret_cast<const float2*>(xf + (size_t)src * C_IN + 2 * lane);
                a0 += w.x; a1 += w.y;
            }
        } else {
            const u16* xh = (const u16*)xv;
            u32 v = *reinterpret_cast<const u32*>(xh + (size_t)node * C_IN + 2 * lane);
            a0 = bf2f_lo(v); a1 = bf2f_hi(v);
            for (int t = s; t < e; ++t) {
                const int src = col_idx[t];
                u32 w = *reinterpret_cast<const u32*>(xh + (size_t)src * C_IN + 2 * lane);
                a0 += bf2f_lo(w); a1 += bf2f_hi(w);
            }
        }
        outw = pack2(a0, a1);
    }
    *reinterpret_cast<u32*>(z + (size_t)node * HD + 2 * lane) = outw;
}

// Fused BN+lrelu + gather: z[i] = h(u[i]) + sum_{j in N(i)} h(u[j]), h(v)=lrelu(A*v+B)
// coef[0..127]=A, coef[128..255]=B
__global__ __launch_bounds__(256) void agg_bn_kernel(const u16* __restrict__ u, const int* __restrict__ row_ptr,
                                                     const int* __restrict__ col_idx,
                                                     const float* __restrict__ coef, u16* __restrict__ z) {
    const int wave = threadIdx.x >> 6, lane = threadIdx.x & 63;
    const int node = blockIdx.x * 4 + wave;
    if (node >= N_NODES) return;
    const int j0 = 2 * lane;
    const float A0 = coef[j0], A1 = coef[j0 + 1];
    const float B0 = coef[128 + j0], B1 = coef[128 + j0 + 1];
    u32 v = *reinterpret_cast<const u32*>(u + (size_t)node * HD + j0);
    float a0 = lrelu(A0 * bf2f_lo(v) + B0);
    float a1 = lrelu(A1 * bf2f_hi(v) + B1);
    const int s = row_ptr[node], e = row_ptr[node + 1];
    for (int t = s; t < e; ++t) {
        const int src = col_idx[t];
        u32 w = *reinterpret_cast<const u32*>(u + (size_t)src * HD + j0);
        a0 += lrelu(A0 * bf2f_lo(w) + B0);
        a1 += lrelu(A1 * bf2f_hi(w) + B1);
    }
    *reinterpret_cast<u32*>(z + (size_t)node * HD + j0) = pack2(a0, a1);
}

// ---------------- MFMA GEMM: out[M,128] = f(A[M,128]) @ W[128,128] + bias ----------------
// W pre-packed in b-frag layout (wp). TRANS=1 applies lrelu(tAB[k]*a + tAB[128+k]) to A while
// loading fragments. STATS=1 accumulates column sum/sumsq (incl. bias) into stats via atomics.
// IN-PLACE SAFE: each wave reads only its own 32 rows, writes them after all its reads.
template <int TRANS, int STATS>
__global__ __launch_bounds__(256) void gemm_mfma(const u16* A, const u16* __restrict__ wp,
                                                 const void* __restrict__ biasv, size_t belem,
                                                 const float* __restrict__ tAB, const int* __restrict__ mode,
                                                 u16* out, float* __restrict__ stats) {
    __shared__ float sred[4][128];
    __shared__ float sqred[4][128];
    const int md = *mode;
    const int tid = threadIdx.x;
    const int wave = tid >> 6, lane = tid & 63;
    const int quad = lane >> 4, lx = lane & 15;
    const int mrow0 = blockIdx.x * 128 + wave * 32;

    f32x4 acc[2][8] = {};

    #pragma unroll
    for (int kb = 0; kb < 4; ++kb) {
        const int k0 = kb * 32 + quad * 8;
        bf16x8 bfr[8];
        #pragma unroll
        for (int nt = 0; nt < 8; ++nt)
            bfr[nt] = *reinterpret_cast<const bf16x8*>(wp + (((size_t)(kb * 8 + nt) * 64 + lane) << 3));
        #pragma unroll
        for (int ms = 0; ms < 2; ++ms) {
            const int row = mrow0 + ms * 16 + lx;
            bf16x8 af = {0, 0, 0, 0, 0, 0, 0, 0};
            if (row < N_NODES) {
                af = *reinterpret_cast<const bf16x8*>(A + (size_t)row * HD + k0);
                if (TRANS) {
                    #pragma unroll
                    for (int j = 0; j < 8; ++j) {
                        float v = bf2f((u16)af[j]);
                        v = lrelu(tAB[k0 + j] * v + tAB[128 + k0 + j]);
                        af[j] = (short)f2bf(v);
                    }
                }
            }
            #pragma unroll
            for (int nt = 0; nt < 8; ++nt)
                acc[ms][nt] = __builtin_amdgcn_mfma_f32_16x16x32_bf16(af, bfr[nt], acc[ms][nt], 0, 0, 0);
        }
    }

    #pragma unroll
    for (int nt = 0; nt < 8; ++nt) {
        const int n = nt * 16 + lx;
        const float bj = md ? ((const float*)biasv)[belem + n] : bf2f(((const u16*)biasv)[belem + n]);
        float s = 0.f, q = 0.f;
        #pragma unroll
        for (int ms = 0; ms < 2; ++ms) {
            #pragma unroll
            for (int r = 0; r < 4; ++r) {
                const int m = mrow0 + ms * 16 + quad * 4 + r;
                if (m < N_NODES) {
                    const float v = acc[ms][nt][r] + bj;
                    out[(size_t)m * HD + n] = f2bf(v);
                    if (STATS) { s += v; q += v * v; }
                }
            }
        }
        if (STATS) {
            s += __shfl_xor(s, 16); s += __shfl_xor(s, 32);
            q += __shfl_xor(q, 16); q += __shfl_xor(q, 32);
            if (quad == 0) { sred[wave][n] = s; sqred[wave][n] = q; }
        }
    }
    if (STATS) {
        __syncthreads();
        if (tid < 128) {
            const float v = sred[0][tid] + sred[1][tid] + sred[2][tid] + sred[3][tid];
            atomicAdd(&stats[tid], v);
        } else {
            const int c = tid - 128;
            const float v = sqred[0][c] + sqred[1][c] + sqred[2][c] + sqred[3][c];
            atomicAdd(&stats[128 + c], v);
        }
    }
}

// ---------------- BN finalize ----------------
__global__ __launch_bounds__(128) void finalize_kernel(float* __restrict__ stats, const void* __restrict__ gammav,
                                                       const void* __restrict__ betav, size_t elem,
                                                       const int* __restrict__ mode) {
    const int j = threadIdx.x;
    const int md = *mode;
    const float inv_n = 1.0f / (float)N_NODES;
    float mean = stats[j] * inv_n;
    float var = stats[128 + j] * inv_n - mean * mean;
    var = fmaxf(var, 0.f);
    float rs = rsqrtf(var + BN_EPS);
    float g  = md ? ((const float*)gammav)[elem + j] : bf2f(((const u16*)gammav)[elem + j]);
    float be = md ? ((const float*)betav)[elem + j]  : bf2f(((const u16*)betav)[elem + j]);
    float A = g * rs;
    stats[256 + j] = A;
    stats[384 + j] = be - A * mean;
}

// ---------------- pooling + head ----------------
__global__ __launch_bounds__(128) void pool_kernel(const u16* __restrict__ hf, const int* __restrict__ batch,
                                                   const int* __restrict__ mode, float* __restrict__ emb,
                                                   void* __restrict__ outv) {
    const int g = blockIdx.x;
    const int j = threadIdx.x;
    const int md = *mode;
    int lo = 0, hi = N_NODES;
    while (lo < hi) { int m = (lo + hi) >> 1; if (batch[m] < g) lo = m + 1; else hi = m; }
    const int s = lo;
    hi = N_NODES;
    while (lo < hi) { int m = (lo + hi) >> 1; if (batch[m] < g + 1) lo = m + 1; else hi = m; }
    const int e = lo;
    const int cnt = e - s;
    float sum = 0.f, mx = -INFINITY;
    for (int n = s; n < e; ++n) {
        float v = bf2f(hf[(size_t)n * HD + j]);
        sum += v;
        mx = fmaxf(mx, v);
    }
    float mean = sum / (float)max(cnt, 1);
    if (cnt == 0) mx = 0.f;
    emb[(size_t)g * 256 + j] = mean;
    emb[(size_t)g * 256 + 128 + j] = mx;
    const size_t base = (size_t)N_GRAPHS * 3 + (size_t)g * 256;
    if (md) {
        ((float*)outv)[base + j] = mean;
        ((float*)outv)[base + 128 + j] = mx;
    } else {
        ((u16*)outv)[base + j] = f2bf(mean);
        ((u16*)outv)[base + 128 + j] = f2bf(mx);
    }
}

__global__ __launch_bounds__(64) void final_kernel(const float* __restrict__ emb, const void* __restrict__ fcwv,
                                                   const void* __restrict__ fcbv, const void* __restrict__ fc2wv,
                                                   const void* __restrict__ fc2bv, const int* __restrict__ mode,
                                                   void* __restrict__ outv) {
    __shared__ float es[256];
    __shared__ float hs[64];
    const int g = blockIdx.x, t = threadIdx.x;
    const int md = *mode;
    reinterpret_cast<float4*>(es)[t] = reinterpret_cast<const float4*>(emb + (size_t)g * 256)[t];
    __syncthreads();
    float acc = md ? ((const float*)fcbv)[t] : bf2f(((const u16*)fcbv)[t]);
    if (md) {
        const float* w = (const float*)fcwv;
        #pragma unroll 8
        for (int k = 0; k < 256; ++k) acc += es[k] * w[k * 64 + t];
    } else {
        const u16* w = (const u16*)fcwv;
        #pragma unroll 8
        for (int k = 0; k < 256; ++k) acc += es[k] * bf2f(w[k * 64 + t]);
    }
    hs[t] = lrelu(acc);
    __syncthreads();
    if (t < 3) {
        float o = md ? ((const float*)fc2bv)[t] : bf2f(((const u16*)fc2bv)[t]);
        if (md) {
            const float* w = (const float*)fc2wv;
            #pragma unroll 8
            for (int j = 0; j < 64; ++j) o += hs[j] * w[j * 3 + t];
            ((float*)outv)[(size_t)g * 3 + t] = o;
        } else {
            const u16* w = (const u16*)fc2wv;
            #pragma unroll 8
            for (int j = 0; j < 64; ++j) o += hs[j] * bf2f(w[j * 3 + t]);
            ((u16*)outv)[(size_t)g * 3 + t] = f2bf(o);
        }
    }
}

// ---------------- launch ----------------
static inline size_t align256(size_t x) { return (x + 255) & ~(size_t)255; }

extern "C" void kernel_launch(void* const* d_in, const int* in_sizes, int n_in,
                              void* d_out, int out_size, void* d_ws, size_t ws_size,
                              hipStream_t stream) {
    (void)in_sizes; (void)n_in; (void)out_size; (void)ws_size;
    const void* x    = d_in[0];
    const void* W1a  = d_in[2];
    const void* W1b  = d_in[3];
    const void* b1   = d_in[4];
    const void* g1   = d_in[5];
    const void* be1  = d_in[6];
    const void* W2   = d_in[7];
    const void* b2   = d_in[8];
    const void* gn   = d_in[9];
    const void* bnb  = d_in[10];
    const void* fcw  = d_in[11];
    const void* fcb  = d_in[12];
    const void* fc2w = d_in[13];
    const void* fc2b = d_in[14];
    const int* ei    = (const int*)d_in[15];
    const int* batch = (const int*)d_in[16];

    char* p = (char*)d_ws;
    size_t off = 0;
    u16* zb = (u16*)(p + off); off += align256((size_t)N_NODES * HD * 2);
    u16* hb = (u16*)(p + off); off += align256((size_t)N_NODES * HD * 2);
    u16* wpack = (u16*)(p + off); off += align256((size_t)12 * HD * HD * 2);
    float* emb = (float*)(p + off); off += align256((size_t)N_GRAPHS * 256 * 4);
    int* row_ptr = (int*)(p + off); off += align256((size_t)(N_NODES + 1) * 4);
    int* cursor = (int*)(p + off); off += align256((size_t)N_NODES * 4);
    int* col_idx = (int*)(p + off); off += align256((size_t)N_EDGES * 4);
    int* bsum = (int*)(p + off); off += align256((size_t)SB * 4);
    float* statsA = (float*)(p + off); off += align256(512 * 4);
    float* statsB = (float*)(p + off); off += align256(512 * 4);
    int* mode = (int*)(p + off); off += align256(4);

    const int EB = (N_EDGES + 255) / 256;
    const int AB = (N_NODES + 3) / 4;
    const int GBM = (N_NODES + 127) / 128;  // 782

    detect_kernel<<<1, 256, 0, stream>>>((const u16*)x, mode);

    hipMemsetAsync(cursor, 0, (size_t)N_NODES * 4, stream);
    hist_kernel<<<EB, 256, 0, stream>>>(ei + N_EDGES, cursor);
    scan1_kernel<<<SB, 256, 0, stream>>>(cursor, bsum);
    scan2_kernel<<<1, 512, 0, stream>>>(bsum, row_ptr);
    scan3_kernel<<<SB, 256, 0, stream>>>(cursor, bsum, row_ptr);
    hipMemcpyAsync(cursor, row_ptr, (size_t)N_NODES * 4, hipMemcpyDeviceToDevice, stream);
    fill_kernel<<<EB, 256, 0, stream>>>(ei, ei + N_EDGES, cursor, col_idx);
    pack_w_kernel<<<96, 256, 0, stream>>>(W1a, W1b, W2, mode, wpack);

    u16* cur = zb;
    u16* oth = hb;
    for (int l = 0; l < NLAYERS; ++l) {
        if (l == 0) {
            agg0_kernel<<<AB, 256, 0, stream>>>(x, row_ptr, col_idx, mode, cur);
        } else {
            agg_bn_kernel<<<AB, 256, 0, stream>>>(cur, row_ptr, col_idx, statsB + 256, oth);
            u16* t = cur; cur = oth; oth = t;
        }
        const size_t voff = (size_t)l * HD;
        hipMemsetAsync(statsA, 0, 256 * 4, stream);
        gemm_mfma<0, 1><<<GBM, 256, 0, stream>>>(cur, wpack + (size_t)l * HD * HD, b1, voff,
                                                 nullptr, mode, cur, statsA);
        finalize_kernel<<<1, 128, 0, stream>>>(statsA, g1, be1, voff, mode);
        if (l < NLAYERS - 1) {
            hipMemsetAsync(statsB, 0, 256 * 4, stream);
            gemm_mfma<1, 1><<<GBM, 256, 0, stream>>>(cur, wpack + (size_t)(6 + l) * HD * HD, b2, voff,
                                                     statsA + 256, mode, cur, statsB);
            finalize_kernel<<<1, 128, 0, stream>>>(statsB, gn, bnb, voff, mode);
        } else {
            gemm_mfma<1, 0><<<GBM, 256, 0, stream>>>(cur, wpack + (size_t)(6 + l) * HD * HD, b2, voff,
                                                     statsA + 256, mode, cur, nullptr);
        }
    }

    pool_kernel<<<N_GRAPHS, 128, 0, stream>>>(cur, batch, mode, emb, d_out);
    final_kernel<<<N_GRAPHS, 64, 0, stream>>>(emb, fcw, fcb, fc2w, fc2b, mode, d_out);
}

// Round 5
// 1036.432 us; speedup vs baseline: 1.9792x; 1.0701x over previous
//
#include <hip/hip_runtime.h>
#include <stdint.h>

#define N_NODES 100000
#define N_EDGES 400000
#define N_GRAPHS 2000
#define C_IN 48
#define HD 128
#define NLAYERS 6
#define BN_EPS 1e-5f
#define NSLOPE 0.01f
#define SB 391  // ceil(N_NODES/256)

typedef uint16_t u16;
typedef uint32_t u32;
typedef short bf16x8 __attribute__((ext_vector_type(8)));
typedef float f32x4 __attribute__((ext_vector_type(4)));

__device__ __forceinline__ float bf2f_lo(u32 v) { return __uint_as_float(v << 16); }
__device__ __forceinline__ float bf2f_hi(u32 v) { return __uint_as_float(v & 0xffff0000u); }
__device__ __forceinline__ float bf2f(u16 h) { return __uint_as_float(((u32)h) << 16); }
__device__ __forceinline__ u16 f2bf(float f) {
    u32 u = __float_as_uint(f);
    u32 r = (u + 0x7fffu + ((u >> 16) & 1u)) >> 16;
    return (u16)r;
}
__device__ __forceinline__ u32 pack2(float a, float b) {
    return (u32)f2bf(a) | ((u32)f2bf(b) << 16);
}
__device__ __forceinline__ float lrelu(float v) { return v >= 0.f ? v : v * NSLOPE; }

// dtype detection: mode=1 -> float inputs are fp32; mode=0 -> bf16.
__global__ __launch_bounds__(256) void detect_kernel(const u16* __restrict__ x, int* __restrict__ mode) {
    __shared__ int flag;
    if (threadIdx.x == 0) flag = 0;
    __syncthreads();
    int local = 0;
    for (int i = threadIdx.x; i < 16384; i += 256) {
        float a = fabsf(bf2f(x[i]));
        if (!(a < 1e4f)) local = 1;
    }
    if (local) flag = 1;
    __syncthreads();
    if (threadIdx.x == 0) mode[0] = flag;
}

// ---------------- CSR build ----------------
__global__ __launch_bounds__(256) void hist_kernel(const int* __restrict__ dst, int* __restrict__ cnt) {
    int e = blockIdx.x * 256 + threadIdx.x;
    if (e < N_EDGES) atomicAdd(&cnt[dst[e]], 1);
}

__global__ __launch_bounds__(256) void scan1_kernel(const int* __restrict__ cnt, int* __restrict__ bsum) {
    __shared__ int s[256];
    const int t = threadIdx.x;
    const int i = blockIdx.x * 256 + t;
    s[t] = (i < N_NODES) ? cnt[i] : 0;
    __syncthreads();
    for (int d = 128; d > 0; d >>= 1) {
        if (t < d) s[t] += s[t + d];
        __syncthreads();
    }
    if (t == 0) bsum[blockIdx.x] = s[0];
}

__global__ __launch_bounds__(512) void scan2_kernel(int* __restrict__ bsum, int* __restrict__ row_ptr) {
    __shared__ int s[SB];
    const int t = threadIdx.x;
    if (t < SB) s[t] = bsum[t];
    __syncthreads();
    if (t == 0) {
        int run = 0;
        for (int b = 0; b < SB; ++b) { int v = s[b]; s[b] = run; run += v; }
        row_ptr[0] = 0;
    }
    __syncthreads();
    if (t < SB) bsum[t] = s[t];
}

__global__ __launch_bounds__(256) void scan3_kernel(const int* __restrict__ cnt, const int* __restrict__ bsum,
                                                    int* __restrict__ row_ptr) {
    __shared__ int s[256];
    const int t = threadIdx.x;
    const int i = blockIdx.x * 256 + t;
    s[t] = (i < N_NODES) ? cnt[i] : 0;
    __syncthreads();
    if (t == 0) {
        int run = bsum[blockIdx.x];
        for (int j = 0; j < 256; ++j) { run += s[j]; s[j] = run; }
    }
    __syncthreads();
    if (i < N_NODES) row_ptr[i + 1] = s[t];
}

__global__ __launch_bounds__(256) void fill_kernel(const int* __restrict__ src, const int* __restrict__ dst,
                                                   int* __restrict__ cursor, int* __restrict__ col_idx) {
    int e = blockIdx.x * 256 + threadIdx.x;
    if (e < N_EDGES) {
        int d = dst[e];
        int slot = atomicAdd(&cursor[d], 1);
        col_idx[slot] = src[e];
    }
}

// ---------------- weight pre-pack into MFMA B-fragment layout (bf16) ----------------
__global__ __launch_bounds__(256) void pack_w_kernel(const void* __restrict__ W1a, const void* __restrict__ W1b,
                                                     const void* __restrict__ W2, const int* __restrict__ mode,
                                                     u16* __restrict__ wpack) {
    const int t = blockIdx.x * 256 + threadIdx.x;  // 12*2048 = 24576
    if (t >= 24576) return;
    const int mat = t >> 11;
    const int r = t & 2047;
    const int l = r & 63;
    const int f = r >> 6;
    const int kb = f >> 3, nt = f & 7;
    const int k0 = kb * 32 + (l >> 4) * 8;
    const int n = nt * 16 + (l & 15);
    const int md = *mode;
    u16 vals[8];
    #pragma unroll
    for (int j = 0; j < 8; ++j) {
        const int k = k0 + j;
        float v;
        if (mat == 0) {
            v = (k < C_IN) ? (md ? ((const float*)W1a)[k * HD + n] : bf2f(((const u16*)W1a)[k * HD + n])) : 0.f;
        } else if (mat < 6) {
            const size_t o = (size_t)(mat - 1) * HD * HD + (size_t)k * HD + n;
            v = md ? ((const float*)W1b)[o] : bf2f(((const u16*)W1b)[o]);
        } else {
            const size_t o = (size_t)(mat - 6) * HD * HD + (size_t)k * HD + n;
            v = md ? ((const float*)W2)[o] : bf2f(((const u16*)W2)[o]);
        }
        vals[j] = f2bf(v);
    }
    uint4 o;
    o.x = (u32)vals[0] | ((u32)vals[1] << 16);
    o.y = (u32)vals[2] | ((u32)vals[3] << 16);
    o.z = (u32)vals[4] | ((u32)vals[5] << 16);
    o.w = (u32)vals[6] | ((u32)vals[7] << 16);
    *reinterpret_cast<uint4*>(wpack + (size_t)t * 8) = o;
}

// ---------------- aggregation (batched gather) ----------------
__global__ __launch_bounds__(256) void agg0_kernel(const void* __restrict__ xv, const int* __restrict__ row_ptr,
                                                   const int* __restrict__ col_idx, const int* __restrict__ mode,
                                                   u16* __restrict__ z) {
    const int wave = threadIdx.x >> 6, lane = threadIdx.x & 63;
    const int node = blockIdx.x * 4 + wave;
    if (node >= N_NODES) return;
    const int md = *mode;
    const int s = row_ptr[node];
    const int deg = row_ptr[node + 1] - s;
    float a0 = 0.f, a1 = 0.f;
    if (md) {
        const float* xf = (const float*)xv;
        if (lane < 24) {
            float2 v = *reinterpret_cast<const float2*>(xf + (size_t)node * C_IN + 2 * lane);
            a0 = v.x; a1 = v.y;
        }
        int done = 0;
        while (done < deg) {
            const int n = min(deg - done, 64);
            int idx = (lane < n) ? col_idx[s + done + lane] : 0;
            for (int b = 0; b < n; b += 4) {
                const int i0 = __shfl(idx, b + 0);
                const int i1 = __shfl(idx, b + 1);
                const int i2 = __shfl(idx, b + 2);
                const int i3 = __shfl(idx, b + 3);
                if (lane < 24) {
                    float2 w0 = *reinterpret_cast<const float2*>(xf + (size_t)i0 * C_IN + 2 * lane);
                    float2 w1 = make_float2(0.f, 0.f), w2 = make_float2(0.f, 0.f), w3 = make_float2(0.f, 0.f);
                    if (b + 1 < n) w1 = *reinterpret_cast<const float2*>(xf + (size_t)i1 * C_IN + 2 * lane);
                    if (b + 2 < n) w2 = *reinterpret_cast<const float2*>(xf + (size_t)i2 * C_IN + 2 * lane);
                    if (b + 3 < n) w3 = *reinterpret_cast<const float2*>(xf + (size_t)i3 * C_IN + 2 * lane);
                    a0 += w0.x + w1.x + w2.x + w3.x;
                    a1 += w0.y + w1.y + w2.y + w3.y;
                }
            }
            done += n;
        }
    } else {
        const u16* xh = (const u16*)xv;
        if (lane < 24) {
            u32 v = *reinterpret_cast<const u32*>(xh + (size_t)node * C_IN + 2 * lane);
            a0 = bf2f_lo(v); a1 = bf2f_hi(v);
        }
        int done = 0;
        while (done < deg) {
            const int n = min(deg - done, 64);
            int idx = (lane < n) ? col_idx[s + done + lane] : 0;
            for (int b = 0; b < n; b += 4) {
                const int i0 = __shfl(idx, b + 0);
                const int i1 = __shfl(idx, b + 1);
                const int i2 = __shfl(idx, b + 2);
                const int i3 = __shfl(idx, b + 3);
                if (lane < 24) {
                    u32 w0 = *reinterpret_cast<const u32*>(xh + (size_t)i0 * C_IN + 2 * lane);
                    u32 w1 = 0, w2 = 0, w3 = 0;
                    if (b + 1 < n) w1 = *reinterpret_cast<const u32*>(xh + (size_t)i1 * C_IN + 2 * lane);
                    if (b + 2 < n) w2 = *reinterpret_cast<const u32*>(xh + (size_t)i2 * C_IN + 2 * lane);
                    if (b + 3 < n) w3 = *reinterpret_cast<const u32*>(xh + (size_t)i3 * C_IN + 2 * lane);
                    a0 += bf2f_lo(w0) + bf2f_lo(w1) + bf2f_lo(w2) + bf2f_lo(w3);
                    a1 += bf2f_hi(w0) + bf2f_hi(w1) + bf2f_hi(w2) + bf2f_hi(w3);
                }
            }
            done += n;
        }
    }
    u32 outw = (lane < 24) ? pack2(a0, a1) : 0u;
    *reinterpret_cast<u32*>(z + (size_t)node * HD + 2 * lane) = outw;
}

// Fused outer-BN+lrelu + gather; BN coefs computed inline from raw stats.
__global__ __launch_bounds__(256) void agg_bn_kernel(const u16* __restrict__ u, const int* __restrict__ row_ptr,
                                                     const int* __restrict__ col_idx,
                                                     const float* __restrict__ stats,
                                                     const void* __restrict__ gammav, const void* __restrict__ betav,
                                                     size_t gelem, const int* __restrict__ mode,
                                                     u16* __restrict__ z) {
    const int wave = threadIdx.x >> 6, lane = threadIdx.x & 63;
    const int node = blockIdx.x * 4 + wave;
    if (node >= N_NODES) return;
    const int md = *mode;
    const int j0 = 2 * lane;
    const float inv_n = 1.0f / (float)N_NODES;
    const float mean0 = stats[j0] * inv_n, mean1 = stats[j0 + 1] * inv_n;
    const float var0 = fmaxf(stats[128 + j0] * inv_n - mean0 * mean0, 0.f);
    const float var1 = fmaxf(stats[128 + j0 + 1] * inv_n - mean1 * mean1, 0.f);
    const float g0 = md ? ((const float*)gammav)[gelem + j0] : bf2f(((const u16*)gammav)[gelem + j0]);
    const float g1v = md ? ((const float*)gammav)[gelem + j0 + 1] : bf2f(((const u16*)gammav)[gelem + j0 + 1]);
    const float be0 = md ? ((const float*)betav)[gelem + j0] : bf2f(((const u16*)betav)[gelem + j0]);
    const float be1 = md ? ((const float*)betav)[gelem + j0 + 1] : bf2f(((const u16*)betav)[gelem + j0 + 1]);
    const float A0 = g0 * rsqrtf(var0 + BN_EPS), B0 = be0 - A0 * mean0;
    const float A1 = g1v * rsqrtf(var1 + BN_EPS), B1 = be1 - A1 * mean1;

    u32 v = *reinterpret_cast<const u32*>(u + (size_t)node * HD + j0);
    float a0 = lrelu(A0 * bf2f_lo(v) + B0);
    float a1 = lrelu(A1 * bf2f_hi(v) + B1);
    const int s = row_ptr[node];
    const int deg = row_ptr[node + 1] - s;
    int done = 0;
    while (done < deg) {
        const int n = min(deg - done, 64);
        int idx = (lane < n) ? col_idx[s + done + lane] : 0;
        for (int b = 0; b < n; b += 4) {
            const int i0 = __shfl(idx, b + 0);
            const int i1 = __shfl(idx, b + 1);
            const int i2 = __shfl(idx, b + 2);
            const int i3 = __shfl(idx, b + 3);
            const u32 w0 = *reinterpret_cast<const u32*>(u + (size_t)i0 * HD + j0);
            u32 w1 = 0, w2 = 0, w3 = 0;
            if (b + 1 < n) w1 = *reinterpret_cast<const u32*>(u + (size_t)i1 * HD + j0);
            if (b + 2 < n) w2 = *reinterpret_cast<const u32*>(u + (size_t)i2 * HD + j0);
            if (b + 3 < n) w3 = *reinterpret_cast<const u32*>(u + (size_t)i3 * HD + j0);
            a0 += lrelu(A0 * bf2f_lo(w0) + B0);
            a1 += lrelu(A1 * bf2f_hi(w0) + B1);
            if (b + 1 < n) { a0 += lrelu(A0 * bf2f_lo(w1) + B0); a1 += lrelu(A1 * bf2f_hi(w1) + B1); }
            if (b + 2 < n) { a0 += lrelu(A0 * bf2f_lo(w2) + B0); a1 += lrelu(A1 * bf2f_hi(w2) + B1); }
            if (b + 3 < n) { a0 += lrelu(A0 * bf2f_lo(w3) + B0); a1 += lrelu(A1 * bf2f_hi(w3) + B1); }
        }
        done += n;
    }
    *reinterpret_cast<u32*>(z + (size_t)node * HD + j0) = pack2(a0, a1);
}

// ---------------- MFMA GEMM with LDS-staged A ----------------
// out[M,128] = f(A[M,128]) @ W + bias; TRANS applies inner-BN+lrelu (coefs from raw instats)
// while staging A into LDS. STATS accumulates column sum/sumsq of (acc+bias) into stats.
// IN-PLACE SAFE (out == A): block reads A rows [m0,m0+128) only in staging; writes them after.
template <int TRANS, int STATS>
__global__ __launch_bounds__(256) void gemm_mfma(const u16* A, const u16* __restrict__ wp,
                                                 const void* __restrict__ biasv, size_t belem,
                                                 const float* __restrict__ instats,
                                                 const void* __restrict__ gammav, const void* __restrict__ betav,
                                                 size_t gelem, const int* __restrict__ mode,
                                                 u16* out, float* __restrict__ stats) {
    __shared__ u16 Asm[128][136];  // 272 B row stride: 2-way (free) bank pattern
    __shared__ float sred[4][128];
    __shared__ float sqred[4][128];
    const int md = *mode;
    const int tid = threadIdx.x;
    const int m0 = blockIdx.x * 128;

    // ---- stage A tile (+ optional BN+lrelu) into LDS: 8 independent uint4 loads/thread ----
    {
        const int rbase = tid >> 4;   // 0..15
        const int seg = tid & 15;     // cols seg*8 .. seg*8+7
        float cA[8], cB[8];
        if (TRANS) {
            const float inv_n = 1.0f / (float)N_NODES;
            #pragma unroll
            for (int j = 0; j < 8; ++j) {
                const int c = seg * 8 + j;
                const float mean = instats[c] * inv_n;
                const float var = fmaxf(instats[128 + c] * inv_n - mean * mean, 0.f);
                const float rs = rsqrtf(var + BN_EPS);
                const float g  = md ? ((const float*)gammav)[gelem + c] : bf2f(((const u16*)gammav)[gelem + c]);
                const float be = md ? ((const float*)betav)[gelem + c]  : bf2f(((const u16*)betav)[gelem + c]);
                cA[j] = g * rs;
                cB[j] = be - cA[j] * mean;
            }
        }
        uint4 v[8];
        #pragma unroll
        for (int i = 0; i < 8; ++i) {
            const int gm = m0 + i * 16 + rbase;
            if (gm < N_NODES) v[i] = *reinterpret_cast<const uint4*>(A + (size_t)gm * HD + seg * 8);
            else { v[i].x = 0; v[i].y = 0; v[i].z = 0; v[i].w = 0; }
        }
        #pragma unroll
        for (int i = 0; i < 8; ++i) {
            uint4 o = v[i];
            if (TRANS) {
                u32 w[4] = {o.x, o.y, o.z, o.w};
                #pragma unroll
                for (int q = 0; q < 4; ++q) {
                    const float lo = lrelu(cA[2 * q] * bf2f_lo(w[q]) + cB[2 * q]);
                    const float hi = lrelu(cA[2 * q + 1] * bf2f_hi(w[q]) + cB[2 * q + 1]);
                    w[q] = pack2(lo, hi);
                }
                o.x = w[0]; o.y = w[1]; o.z = w[2]; o.w = w[3];
            }
            *reinterpret_cast<uint4*>(&Asm[i * 16 + rbase][seg * 8]) = o;
        }
    }
    __syncthreads();

    // ---- MFMA phase: A from LDS, W frags from L2 ----
    const int wave = tid >> 6, lane = tid & 63;
    const int quad = lane >> 4, lx = lane & 15;
    const int wrow0 = wave * 32;
    f32x4 acc[2][8] = {};
    #pragma unroll 2
    for (int kb = 0; kb < 4; ++kb) {
        bf16x8 bfr[8];
        #pragma unroll
        for (int nt = 0; nt < 8; ++nt)
            bfr[nt] = *reinterpret_cast<const bf16x8*>(wp + (((size_t)(kb * 8 + nt) * 64 + lane) << 3));
        const int k0 = kb * 32 + quad * 8;
        #pragma unroll
        for (int ms = 0; ms < 2; ++ms) {
            const bf16x8 af = *reinterpret_cast<const bf16x8*>(&Asm[wrow0 + ms * 16 + lx][k0]);
            #pragma unroll
            for (int nt = 0; nt < 8; ++nt)
                acc[ms][nt] = __builtin_amdgcn_mfma_f32_16x16x32_bf16(af, bfr[nt], acc[ms][nt], 0, 0, 0);
        }
    }

    // ---- epilogue: bias, store, optional stats ----
    const int mrow0 = m0 + wave * 32;
    #pragma unroll
    for (int nt = 0; nt < 8; ++nt) {
        const int n = nt * 16 + lx;
        const float bj = md ? ((const float*)biasv)[belem + n] : bf2f(((const u16*)biasv)[belem + n]);
        float s = 0.f, q = 0.f;
        #pragma unroll
        for (int ms = 0; ms < 2; ++ms) {
            #pragma unroll
            for (int r = 0; r < 4; ++r) {
                const int m = mrow0 + ms * 16 + quad * 4 + r;
                if (m < N_NODES) {
                    const float v = acc[ms][nt][r] + bj;
                    out[(size_t)m * HD + n] = f2bf(v);
                    if (STATS) { s += v; q += v * v; }
                }
            }
        }
        if (STATS) {
            s += __shfl_xor(s, 16); s += __shfl_xor(s, 32);
            q += __shfl_xor(q, 16); q += __shfl_xor(q, 32);
            if (quad == 0) { sred[wave][n] = s; sqred[wave][n] = q; }
        }
    }
    if (STATS) {
        __syncthreads();
        if (tid < 128) {
            atomicAdd(&stats[tid], sred[0][tid] + sred[1][tid] + sred[2][tid] + sred[3][tid]);
        } else {
            const int c = tid - 128;
            atomicAdd(&stats[128 + c], sqred[0][c] + sqred[1][c] + sqred[2][c] + sqred[3][c]);
        }
    }
}

// ---------------- pooling + head ----------------
__global__ __launch_bounds__(128) void pool_kernel(const u16* __restrict__ hf, const int* __restrict__ batch,
                                                   const int* __restrict__ mode, float* __restrict__ emb,
                                                   void* __restrict__ outv) {
    const int g = blockIdx.x;
    const int j = threadIdx.x;
    const int md = *mode;
    int lo = 0, hi = N_NODES;
    while (lo < hi) { int m = (lo + hi) >> 1; if (batch[m] < g) lo = m + 1; else hi = m; }
    const int s = lo;
    hi = N_NODES;
    while (lo < hi) { int m = (lo + hi) >> 1; if (batch[m] < g + 1) lo = m + 1; else hi = m; }
    const int e = lo;
    const int cnt = e - s;
    float sum = 0.f, mx = -INFINITY;
    for (int n = s; n < e; ++n) {
        float v = bf2f(hf[(size_t)n * HD + j]);
        sum += v;
        mx = fmaxf(mx, v);
    }
    float mean = sum / (float)max(cnt, 1);
    if (cnt == 0) mx = 0.f;
    emb[(size_t)g * 256 + j] = mean;
    emb[(size_t)g * 256 + 128 + j] = mx;
    const size_t base = (size_t)N_GRAPHS * 3 + (size_t)g * 256;
    if (md) {
        ((float*)outv)[base + j] = mean;
        ((float*)outv)[base + 128 + j] = mx;
    } else {
        ((u16*)outv)[base + j] = f2bf(mean);
        ((u16*)outv)[base + 128 + j] = f2bf(mx);
    }
}

__global__ __launch_bounds__(64) void final_kernel(const float* __restrict__ emb, const void* __restrict__ fcwv,
                                                   const void* __restrict__ fcbv, const void* __restrict__ fc2wv,
                                                   const void* __restrict__ fc2bv, const int* __restrict__ mode,
                                                   void* __restrict__ outv) {
    __shared__ float es[256];
    __shared__ float hs[64];
    const int g = blockIdx.x, t = threadIdx.x;
    const int md = *mode;
    reinterpret_cast<float4*>(es)[t] = reinterpret_cast<const float4*>(emb + (size_t)g * 256)[t];
    __syncthreads();
    float acc = md ? ((const float*)fcbv)[t] : bf2f(((const u16*)fcbv)[t]);
    if (md) {
        const float* w = (const float*)fcwv;
        #pragma unroll 8
        for (int k = 0; k < 256; ++k) acc += es[k] * w[k * 64 + t];
    } else {
        const u16* w = (const u16*)fcwv;
        #pragma unroll 8
        for (int k = 0; k < 256; ++k) acc += es[k] * bf2f(w[k * 64 + t]);
    }
    hs[t] = lrelu(acc);
    __syncthreads();
    if (t < 3) {
        float o = md ? ((const float*)fc2bv)[t] : bf2f(((const u16*)fc2bv)[t]);
        if (md) {
            const float* w = (const float*)fc2wv;
            #pragma unroll 8
            for (int j = 0; j < 64; ++j) o += hs[j] * w[j * 3 + t];
            ((float*)outv)[(size_t)g * 3 + t] = o;
        } else {
            const u16* w = (const u16*)fc2wv;
            #pragma unroll 8
            for (int j = 0; j < 64; ++j) o += hs[j] * bf2f(w[j * 3 + t]);
            ((u16*)outv)[(size_t)g * 3 + t] = f2bf(o);
        }
    }
}

// ---------------- launch ----------------
static inline size_t align256(size_t x) { return (x + 255) & ~(size_t)255; }

extern "C" void kernel_launch(void* const* d_in, const int* in_sizes, int n_in,
                              void* d_out, int out_size, void* d_ws, size_t ws_size,
                              hipStream_t stream) {
    (void)in_sizes; (void)n_in; (void)out_size; (void)ws_size;
    const void* x    = d_in[0];
    const void* W1a  = d_in[2];
    const void* W1b  = d_in[3];
    const void* b1   = d_in[4];
    const void* g1   = d_in[5];
    const void* be1  = d_in[6];
    const void* W2   = d_in[7];
    const void* b2   = d_in[8];
    const void* gn   = d_in[9];
    const void* bnb  = d_in[10];
    const void* fcw  = d_in[11];
    const void* fcb  = d_in[12];
    const void* fc2w = d_in[13];
    const void* fc2b = d_in[14];
    const int* ei    = (const int*)d_in[15];
    const int* batch = (const int*)d_in[16];

    char* p = (char*)d_ws;
    size_t off = 0;
    u16* zb = (u16*)(p + off); off += align256((size_t)N_NODES * HD * 2);
    u16* hb = (u16*)(p + off); off += align256((size_t)N_NODES * HD * 2);
    u16* wpack = (u16*)(p + off); off += align256((size_t)12 * HD * HD * 2);
    float* emb = (float*)(p + off); off += align256((size_t)N_GRAPHS * 256 * 4);
    int* row_ptr = (int*)(p + off); off += align256((size_t)(N_NODES + 1) * 4);
    int* cursor = (int*)(p + off); off += align256((size_t)N_NODES * 4);
    int* col_idx = (int*)(p + off); off += align256((size_t)N_EDGES * 4);
    int* bsum = (int*)(p + off); off += align256((size_t)SB * 4);
    float* statsAB = (float*)(p + off); off += align256(1024 * 4);
    int* mode = (int*)(p + off); off += align256(4);
    float* statsA = statsAB;
    float* statsB = statsAB + 512;

    const int EB = (N_EDGES + 255) / 256;
    const int AB = (N_NODES + 3) / 4;
    const int GBM = (N_NODES + 127) / 128;  // 782

    detect_kernel<<<1, 256, 0, stream>>>((const u16*)x, mode);

    hipMemsetAsync(cursor, 0, (size_t)N_NODES * 4, stream);
    hist_kernel<<<EB, 256, 0, stream>>>(ei + N_EDGES, cursor);
    scan1_kernel<<<SB, 256, 0, stream>>>(cursor, bsum);
    scan2_kernel<<<1, 512, 0, stream>>>(bsum, row_ptr);
    scan3_kernel<<<SB, 256, 0, stream>>>(cursor, bsum, row_ptr);
    hipMemcpyAsync(cursor, row_ptr, (size_t)N_NODES * 4, hipMemcpyDeviceToDevice, stream);
    fill_kernel<<<EB, 256, 0, stream>>>(ei, ei + N_EDGES, cursor, col_idx);
    pack_w_kernel<<<96, 256, 0, stream>>>(W1a, W1b, W2, mode, wpack);

    u16* cur = zb;
    u16* oth = hb;
    for (int l = 0; l < NLAYERS; ++l) {
        if (l == 0) {
            agg0_kernel<<<AB, 256, 0, stream>>>(x, row_ptr, col_idx, mode, cur);
        } else {
            agg_bn_kernel<<<AB, 256, 0, stream>>>(cur, row_ptr, col_idx, statsB, gn, bnb,
                                                  (size_t)(l - 1) * HD, mode, oth);
            u16* t = cur; cur = oth; oth = t;
        }
        const size_t voff = (size_t)l * HD;
        hipMemsetAsync(statsAB, 0, 1024 * sizeof(float), stream);  // zero statsA+statsB
        gemm_mfma<0, 1><<<GBM, 256, 0, stream>>>(cur, wpack + (size_t)l * HD * HD, b1, voff,
                                                 nullptr, g1, be1, voff, mode, cur, statsA);
        if (l < NLAYERS - 1) {
            gemm_mfma<1, 1><<<GBM, 256, 0, stream>>>(cur, wpack + (size_t)(6 + l) * HD * HD, b2, voff,
                                                     statsA, g1, be1, voff, mode, cur, statsB);
        } else {
            gemm_mfma<1, 0><<<GBM, 256, 0, stream>>>(cur, wpack + (size_t)(6 + l) * HD * HD, b2, voff,
                                                     statsA, g1, be1, voff, mode, cur, nullptr);
        }
    }

    pool_kernel<<<N_GRAPHS, 128, 0, stream>>>(cur, batch, mode, emb, d_out);
    final_kernel<<<N_GRAPHS, 64, 0, stream>>>(emb, fcw, fcb, fc2w, fc2b, mode, d_out);
}